// Round 16
// baseline (116.351 us; speedup 1.0000x reference)
//
#include <hip/hip_runtime.h>
#include <hip/hip_bf16.h>
#include <stdint.h>

#define BATCH 8
#define NPOS 4096   // H*W = 64*64
#define LOG2E 1.4426950408889634f

typedef __attribute__((ext_vector_type(4)))  float f32x4;
typedef __attribute__((ext_vector_type(16))) float f32x16;
typedef __attribute__((ext_vector_type(8)))  short bf16x8;

// Native 2^x. Raw inline-asm v_exp_f32 is UNSAFE (r6: TRANS hazard invisible).
// Builtin is compiler-visible. r9 lesson: must pair with chunked
// immediate-consume + sched_barrier or the scheduler hoists all 16 exps ->
// spill cliff (r10-r15: pattern works, no spills).
#if __has_builtin(__builtin_amdgcn_exp2f)
#define EXP2(x) __builtin_amdgcn_exp2f(x)
#else
#define EXP2(x) exp2f(x)
#endif

// sched_barrier mask: MFMA|VMEM*|DS* may cross, VALU/TRANS/SALU may not.
#define SOFTMAX_FENCE() __builtin_amdgcn_sched_barrier(0x3F8)

__device__ __forceinline__ unsigned short bf_rne(float f) {
    unsigned u = __float_as_uint(f);
    u += 0x7fffu + ((u >> 16) & 1u);
    return (unsigned short)(u >> 16);
}
__device__ __forceinline__ unsigned cvt_pk_bf16(float lo, float hi) {
    unsigned r;
    asm("v_cvt_pk_bf16_f32 %0, %1, %2" : "=v"(r) : "v"(lo), "v"(hi));
    return r;
}
__device__ __forceinline__ void permswap32(unsigned &a, unsigned &b) {
    asm volatile("v_permlane32_swap_b32 %0, %1" : "+v"(a), "+v"(b));
}

// ---------------------------------------------------------------------------
// FRAGMENT-MAJOR layouts (r13/r15: K -> LDS pipe conflict-free, V -> L2/TCP
// pipe coalesced; SQ_LDS_BANK_CONFLICT = 0 measured in r15):
//   KF[b][st 64][it 2][kk 4][g2 2][r31 32][e 8]  bf16  (4 MB)
//     element = K[key=st*64+it*32+r31][ch=kk*16+g2*8+e]
//   VF[b][st 64][it 2][h 2][c 2][g2 2][r31 32][e 8]  bf16  (4 MB)
//     element = V[ch=h*32+r31][key=st*64+it*32+c*16+g2*8+e]
// A wave reads any fragment as base + lane*16 -> coalesced 1KB (global) or
// conflict-free contiguous (LDS).
// ---------------------------------------------------------------------------

// Kernel 1: both 1x1 convs. Grid 4096 = (b, nb, pass, oq); 64 threads.
__global__ __launch_bounds__(64)
void conv_prep(const float* __restrict__ xlow, const float* __restrict__ xhigh,
               const float* __restrict__ Wl, const float* __restrict__ bl,
               const float* __restrict__ Wh, const float* __restrict__ bh,
               unsigned short* __restrict__ KF, unsigned short* __restrict__ QThi,
               unsigned short* __restrict__ VF, float* __restrict__ R32)
{
    const int id   = blockIdx.x;
    const int b    = id & 7;
    const int rest = id >> 3;
    const int nb   = rest & 63;
    const int pass = (rest >> 6) & 1;  // 0 = low (K), 1 = high (Q/V/R)
    const int oq   = rest >> 7;        // 0..3 channel quarter
    const int t    = threadIdx.x;
    const int n    = nb * 64 + t;
    const int o0   = oq * 16;

    const float* __restrict__ x    = pass ? xhigh : xlow;
    const float* __restrict__ W    = pass ? Wh : Wl;
    const float* __restrict__ bias = pass ? bh : bl;

    float xr[64];
#pragma unroll
    for (int i = 0; i < 64; ++i)
        xr[i] = x[((size_t)(b * 64 + i)) * NPOS + n];

    // VF scatter base: st=nb, it=(t>>5)&1, c=(t>>4)&1, g2=(t>>3)&1, e=t&7;
    // h=oq>>1, r31=(oq&1)*16+oo -> + (oq&1)*256 + oo*16
    char* vbase = (char*)VF + ((size_t)b << 19) + nb * 8192 + ((t >> 5) & 1) * 4096
                + (oq >> 1) * 2048 + ((t >> 4) & 1) * 1024 + ((t >> 3) & 1) * 512
                + (oq & 1) * 256 + (t & 7) * 2;

    unsigned hpack[8];
#pragma unroll
    for (int oo = 0; oo < 16; ++oo) {
        const int o = o0 + oo;
        float acc = bias[o];
#pragma unroll
        for (int i = 0; i < 64; ++i)
            acc = fmaf(W[o * 64 + i], xr[i], acc);   // W reads wave-uniform -> s_load

        if (pass) {
            *(unsigned short*)(vbase + oo * 16) = bf_rne(acc);
            R32[((size_t)(b * 64 + o)) * NPOS + n] = acc;
        }
        unsigned short h = bf_rne(pass ? acc * LOG2E : acc);
        if (oo & 1) hpack[oo >> 1] |= ((unsigned)h) << 16;
        else        hpack[oo >> 1]  = h;
    }

    if (pass) {
        // Q row-major (per-block prologue gather in attn -- once per wave)
        uint4* ph = (uint4*)(QThi + ((size_t)(b * NPOS + n)) * 64 + o0);
        uint4 v0; v0.x = hpack[0]; v0.y = hpack[1]; v0.z = hpack[2]; v0.w = hpack[3];
        uint4 v1; v1.x = hpack[4]; v1.y = hpack[5]; v1.z = hpack[6]; v1.w = hpack[7];
        ph[0] = v0; ph[1] = v1;
    } else {
        // KF frag-major: key=n -> st=nb, it=(t>>5)&1, r31=t&31; kk=oq, g2=oo>>3
        char* kbase = (char*)KF + ((size_t)b << 19) + nb * 8192 + ((t >> 5) & 1) * 4096
                    + oq * 1024 + (t & 31) * 16;
        uint4 v0; v0.x = hpack[0]; v0.y = hpack[1]; v0.z = hpack[2]; v0.w = hpack[3];
        uint4 v1; v1.x = hpack[4]; v1.y = hpack[5]; v1.z = hpack[6]; v1.w = hpack[7];
        *(uint4*)kbase         = v0;   // g2=0
        *(uint4*)(kbase + 512) = v1;   // g2=1
    }
}

// ---------------------------------------------------------------------------
// K staging: one 8KB supertile of KF -> linear LDS; each wave copies a
// contiguous 1KB chunk. global_load_lds source is PER-LANE (+lane*16);
// LDS dest = uniform base + lane*16 (r14 bug lesson).
// ---------------------------------------------------------------------------
__device__ __forceinline__ void stage_k(const unsigned short* __restrict__ KF,
                                        int b, int st, char* dst, int w, int lane)
{
    const char* src = (const char*)KF + ((size_t)b << 19) + (size_t)st * 8192
                    + w * 1024 + lane * 16;
    __builtin_amdgcn_global_load_lds(
        (const __attribute__((address_space(1))) unsigned int*)(const void*)src,
        (__attribute__((address_space(3))) unsigned int*)(void*)(dst + w * 1024),
        16, 0, 0);
}

// ---------------------------------------------------------------------------
// Kernel 2: flash attention partials. 8 waves x 32 q-rows = 256 q/block.
// Grid = 8 b x 16 qb x nsplit(4) = 512 blocks = 2 blocks/CU (r11/r15
// evidence: TLP beyond 16 waves/CU buys nothing; nsplit=4 halves Pacc).
// K: LDS (conflict-free, r15-verified 0 conflicts). V: global frag-major.
// V SOFTWARE PIPELINE (r15 post-mortem: pipes sum instead of overlap; the
// V wait sat right before PV with only softmax to cover it):
//   V(itA) issued BEFORE QK(itA)  -> hides under QK+softmax (~300+ cyc)
//   V(itB) issued right after QK(itA) -> hides under softmax_A+PV_A+QK_B
// FIXED-SCALE softmax (validated r7-r15): p = exp2(sA), plain-sum combine.
// Wave-staggered it order de-locksteps phases. bf16 partials.
// __launch_bounds__(512,4): VGPR cap 128 (r7/r9 spill lessons); V pipeline
// adds ~16 live VGPRs (~80-96 expected; FETCH blowup = spill tripwire).
// ---------------------------------------------------------------------------
__global__ __launch_bounds__(512, 4)
void attn_fused(const unsigned short* __restrict__ KF,
                const unsigned short* __restrict__ QThi,
                const unsigned short* __restrict__ VF,
                unsigned short* __restrict__ Pacc, float* __restrict__ Lp,
                int nsplit)
{
    const int id   = blockIdx.x;
    const int b    = id & 7;            // one batch per XCD
    const int qb   = (id >> 3) & 15;    // q-block (256 rows)
    const int s    = id >> 7;           // KV split index
    const int tid  = threadIdx.x;
    const int w    = tid >> 6;          // 0..7
    const int lane = tid & 63;
    const int r31  = lane & 31;
    const int g2   = lane >> 5;

    const int st0 = (64 * s) / nsplit;
    const int nst = (64 * (s + 1)) / nsplit - st0;

    __shared__ __align__(1024) char smem[16384];   // 2 x 8KB K supertile buffers

    // Q fragments hoisted (B-operand: col=lane&31=q, k=(lane>>5)*8+e)
    const int qrow = qb * 256 + w * 32 + r31;
    bf16x8 qhi[4];
#pragma unroll
    for (int kk = 0; kk < 4; ++kk)
        qhi[kk] = *(const bf16x8*)(QThi + ((size_t)b * NPOS + qrow) * 64 + kk * 16 + g2 * 8);

    f32x16 accO0, accO1;
#pragma unroll
    for (int r = 0; r < 16; ++r) { accO0[r] = 0.f; accO1[r] = 0.f; }
    float l_run = 0.f;

    stage_k(KF, b, st0, smem, w, lane);
    __syncthreads();

    const int itA = (w & 1);        // wave-staggered phase order
    const int itB = itA ^ 1;

    for (int st = 0; st < nst; ++st) {
        char* buf = smem + (st & 1) * 8192;
        if (st + 1 < nst)
            stage_k(KF, b, st0 + st + 1, smem + ((st + 1) & 1) * 8192, w, lane);

        const char* vst = (const char*)VF + ((size_t)b << 19)
                        + (size_t)(st0 + st) * 8192 + lane * 16;

        // ---- V(itA): issue FIRST so latency hides under QK_A + softmax_A ----
        const char* vbA = vst + itA * 4096;
        bf16x8 vA00 = *(const bf16x8*)(vbA);
        bf16x8 vA01 = *(const bf16x8*)(vbA + 1024);
        bf16x8 vA10 = *(const bf16x8*)(vbA + 2048);
        bf16x8 vA11 = *(const bf16x8*)(vbA + 3072);

        // ---- QK^T (itA): K frags from LDS (conflict-free) ----
        f32x16 sA;
#pragma unroll
        for (int r = 0; r < 16; ++r) sA[r] = 0.f;
        {
            const char* Kb = buf + itA * 4096;
            __builtin_amdgcn_s_setprio(1);
#pragma unroll
            for (int kk = 0; kk < 4; ++kk) {
                bf16x8 kh = *(const bf16x8*)(Kb + kk * 1024 + lane * 16);
                sA = __builtin_amdgcn_mfma_f32_32x32x16_bf16(kh, qhi[kk], sA, 0, 0, 0);
            }
            __builtin_amdgcn_s_setprio(0);
        }

        // ---- V(itB) prefetch: hides under softmax_A + PV_A + QK_B ----
        const char* vbB = vst + itB * 4096;
        bf16x8 vB00 = *(const bf16x8*)(vbB);
        bf16x8 vB01 = *(const bf16x8*)(vbB + 1024);
        bf16x8 vB10 = *(const bf16x8*)(vbB + 2048);
        bf16x8 vB11 = *(const bf16x8*)(vbB + 3072);

        // ---- softmax_A (chunked, r9 spill fix) ----
        unsigned wpk[8];
        {
            float lr0 = 0.f, lr1 = 0.f;
#pragma unroll
            for (int h = 0; h < 8; ++h) {
                float pa = EXP2(sA[2 * h]);
                float pb = EXP2(sA[2 * h + 1]);
                wpk[h] = cvt_pk_bf16(pa, pb);
                lr0 += pa;
                lr1 += pb;
                if (h & 1) SOFTMAX_FENCE();
            }
            l_run += lr0 + lr1;
        }
        {
            unsigned a0 = wpk[0], b0 = wpk[2]; permswap32(a0, b0);
            unsigned a1 = wpk[1], b1 = wpk[3]; permswap32(a1, b1);
            unsigned a2 = wpk[4], b2 = wpk[6]; permswap32(a2, b2);
            unsigned a3 = wpk[5], b3 = wpk[7]; permswap32(a3, b3);
            union { unsigned u[4]; bf16x8 v; } fa0, fa1;
            fa0.u[0] = a0; fa0.u[1] = a1; fa0.u[2] = b0; fa0.u[3] = b1;
            fa1.u[0] = a2; fa1.u[1] = a3; fa1.u[2] = b2; fa1.u[3] = b3;

            // ---- PV_A (vA arrived long ago) ----
            __builtin_amdgcn_s_setprio(1);
            accO0 = __builtin_amdgcn_mfma_f32_32x32x16_bf16(vA00, fa0.v, accO0, 0, 0, 0);
            accO0 = __builtin_amdgcn_mfma_f32_32x32x16_bf16(vA01, fa1.v, accO0, 0, 0, 0);
            accO1 = __builtin_amdgcn_mfma_f32_32x32x16_bf16(vA10, fa0.v, accO1, 0, 0, 0);
            accO1 = __builtin_amdgcn_mfma_f32_32x32x16_bf16(vA11, fa1.v, accO1, 0, 0, 0);
            __builtin_amdgcn_s_setprio(0);
        }

        // ---- QK^T (itB) ----
#pragma unroll
        for (int r = 0; r < 16; ++r) sA[r] = 0.f;
        {
            const char* Kb = buf + itB * 4096;
            __builtin_amdgcn_s_setprio(1);
#pragma unroll
            for (int kk = 0; kk < 4; ++kk) {
                bf16x8 kh = *(const bf16x8*)(Kb + kk * 1024 + lane * 16);
                sA = __builtin_amdgcn_mfma_f32_32x32x16_bf16(kh, qhi[kk], sA, 0, 0, 0);
            }
            __builtin_amdgcn_s_setprio(0);
        }

        // ---- softmax_B ----
        {
            float lr0 = 0.f, lr1 = 0.f;
#pragma unroll
            for (int h = 0; h < 8; ++h) {
                float pa = EXP2(sA[2 * h]);
                float pb = EXP2(sA[2 * h + 1]);
                wpk[h] = cvt_pk_bf16(pa, pb);
                lr0 += pa;
                lr1 += pb;
                if (h & 1) SOFTMAX_FENCE();
            }
            l_run += lr0 + lr1;
        }
        {
            unsigned a0 = wpk[0], b0 = wpk[2]; permswap32(a0, b0);
            unsigned a1 = wpk[1], b1 = wpk[3]; permswap32(a1, b1);
            unsigned a2 = wpk[4], b2 = wpk[6]; permswap32(a2, b2);
            unsigned a3 = wpk[5], b3 = wpk[7]; permswap32(a3, b3);
            union { unsigned u[4]; bf16x8 v; } fa0, fa1;
            fa0.u[0] = a0; fa0.u[1] = a1; fa0.u[2] = b0; fa0.u[3] = b1;
            fa1.u[0] = a2; fa1.u[1] = a3; fa1.u[2] = b2; fa1.u[3] = b3;

            // ---- PV_B (vB prefetched) ----
            __builtin_amdgcn_s_setprio(1);
            accO0 = __builtin_amdgcn_mfma_f32_32x32x16_bf16(vB00, fa0.v, accO0, 0, 0, 0);
            accO0 = __builtin_amdgcn_mfma_f32_32x32x16_bf16(vB01, fa1.v, accO0, 0, 0, 0);
            accO1 = __builtin_amdgcn_mfma_f32_32x32x16_bf16(vB10, fa0.v, accO1, 0, 0, 0);
            accO1 = __builtin_amdgcn_mfma_f32_32x32x16_bf16(vB11, fa1.v, accO1, 0, 0, 0);
            __builtin_amdgcn_s_setprio(0);
        }

        __syncthreads();   // K dbuf safety; drains staging vmcnt
    }

    // ---- epilogue: bf16 partials, O^T layout [64 d][256 q]; l reduced once ----
    const float l_tot = l_run + __shfl_xor(l_run, 32, 64);
#pragma unroll
    for (int r = 0; r < 16; ++r) {
        const int d0 = (r & 3) + 8 * (r >> 2) + 4 * g2;
        Pacc[(size_t)id * 16384 + (size_t)d0 * 256 + w * 32 + r31]        = bf_rne(accO0[r]);
        Pacc[(size_t)id * 16384 + (size_t)(d0 + 32) * 256 + w * 32 + r31] = bf_rne(accO1[r]);
    }
    if (g2 == 0)
        Lp[(size_t)id * 256 + w * 32 + r31] = l_tot;
}

// ---------------------------------------------------------------------------
// Kernel 3: combine = plain sum of bf16 partials / sum of l + residual.
// LINE-ONCE reads (r13 fix): s outer, 32B contiguous per thread/split.
// nsplit=4 -> Pacc 16.8 MB -> ~25 MB read vs r15's 42 MB.
// ---------------------------------------------------------------------------
__global__ __launch_bounds__(256)
void attn_combine(const unsigned short* __restrict__ Pacc, const float* __restrict__ Lp,
                  const float* __restrict__ R32, float* __restrict__ out, int nsplit)
{
    const int cid     = blockIdx.x;
    const int quarter = cid & 3;
    const int b       = (cid >> 2) & 7;
    const int qb      = cid >> 5;        // 0..15
    const int t       = threadIdx.x;

    __shared__ float invL[256];

    {
        float L = 0.f;
        for (int s = 0; s < nsplit; ++s)
            L += Lp[(size_t)((s << 7) | (qb << 3) | b) * 256 + t];
        invL[t] = 1.0f / L;
    }
    __syncthreads();

    const int c_loc = t >> 4;                 // 0..15
    const int c     = quarter * 16 + c_loc;   // 0..63
    const int q0    = (t & 15) * 16;          // 0..240

    float acc[16];
#pragma unroll
    for (int i = 0; i < 16; ++i) acc[i] = 0.f;

    for (int s = 0; s < nsplit; ++s) {
        const size_t p = (size_t)((s << 7) | (qb << 3) | b);
        const bf16x8* pp = (const bf16x8*)(Pacc + p * 16384 + (size_t)c * 256 + q0);
#pragma unroll
        for (int h = 0; h < 2; ++h) {
            bf16x8 v = pp[h];
#pragma unroll
            for (int e = 0; e < 8; ++e)
                acc[h * 8 + e] += __uint_as_float(((unsigned)(unsigned short)v[e]) << 16);
        }
    }

    const size_t obase = ((size_t)(b * 64 + c)) * NPOS + qb * 256 + q0;
#pragma unroll
    for (int hv = 0; hv < 4; ++hv) {
        f32x4 rv = *(const f32x4*)(R32 + obase + hv * 4);
        f32x4 v;
#pragma unroll
        for (int e = 0; e < 4; ++e)
            v[e] = acc[hv * 4 + e] * invL[q0 + hv * 4 + e] + rv[e];
        *(f32x4*)(out + obase + hv * 4) = v;
    }
}

// ---------------------------------------------------------------------------
extern "C" void kernel_launch(void* const* d_in, const int* in_sizes, int n_in,
                              void* d_out, int out_size, void* d_ws, size_t ws_size,
                              hipStream_t stream)
{
    const float* xlow  = (const float*)d_in[0];
    const float* xhigh = (const float*)d_in[1];
    const float* Wl    = (const float*)d_in[2];
    const float* bl    = (const float*)d_in[3];
    const float* Wh    = (const float*)d_in[4];
    const float* bh    = (const float*)d_in[5];

    char* ws = (char*)d_ws;
    unsigned short* KF   = (unsigned short*)(ws);                  // 4 MB frag-major
    unsigned short* QThi = (unsigned short*)(ws + ( 4u << 20));    // 4 MB row-major
    unsigned short* VF   = (unsigned short*)(ws + ( 8u << 20));    // 4 MB frag-major
    float*          R32  = (float*)         (ws + (12u << 20));    // 8 MB -> 20 MB

    const size_t base = (size_t)20u << 20;
    // nsplit=4 -> grid 512 = exactly 2 blocks/CU (r11: same attn speed as
    // 4/CU; halves Pacc and combine traffic vs nsplit=8).
    int nsplit = 4;
    while (nsplit > 1) {
        size_t nblk = (size_t)128 * nsplit;
        size_t need = base + nblk * 16384 * 2 + nblk * 256 * 4;
        if (need <= ws_size) break;
        nsplit >>= 1;
    }
    const size_t nblk = (size_t)128 * nsplit;
    unsigned short* Pacc = (unsigned short*)(ws + base);
    float*          Lp   = (float*)(ws + base + nblk * 16384 * 2);

    conv_prep<<<dim3(4096), dim3(64), 0, stream>>>(
        xlow, xhigh, Wl, bl, Wh, bh, KF, QThi, VF, R32);
    attn_fused<<<dim3((unsigned)nblk), dim3(512), 0, stream>>>(
        KF, QThi, VF, Pacc, Lp, nsplit);
    attn_combine<<<dim3(512), dim3(256), 0, stream>>>(
        Pacc, Lp, R32, (float*)d_out, nsplit);
}

// Round 19
// 116.289 us; speedup vs baseline: 1.0005x; 1.0005x over previous
//
#include <hip/hip_runtime.h>
#include <hip/hip_bf16.h>
#include <stdint.h>

#define BATCH 8
#define NPOS 4096   // H*W = 64*64
#define LOG2E 1.4426950408889634f

typedef __attribute__((ext_vector_type(4)))  float f32x4;
typedef __attribute__((ext_vector_type(16))) float f32x16;
typedef __attribute__((ext_vector_type(8)))  short bf16x8;

// Native 2^x. Raw inline-asm v_exp_f32 is UNSAFE (r6: TRANS hazard invisible).
// Builtin is compiler-visible. r9 lesson: must pair with chunked
// immediate-consume + sched_barrier or the scheduler hoists all 16 exps ->
// spill cliff (r10-r15: pattern works, no spills).
#if __has_builtin(__builtin_amdgcn_exp2f)
#define EXP2(x) __builtin_amdgcn_exp2f(x)
#else
#define EXP2(x) exp2f(x)
#endif

// sched_barrier mask: MFMA|VMEM*|DS* may cross, VALU/TRANS/SALU may not.
#define SOFTMAX_FENCE() __builtin_amdgcn_sched_barrier(0x3F8)

__device__ __forceinline__ unsigned short bf_rne(float f) {
    unsigned u = __float_as_uint(f);
    u += 0x7fffu + ((u >> 16) & 1u);
    return (unsigned short)(u >> 16);
}
__device__ __forceinline__ unsigned cvt_pk_bf16(float lo, float hi) {
    unsigned r;
    asm("v_cvt_pk_bf16_f32 %0, %1, %2" : "=v"(r) : "v"(lo), "v"(hi));
    return r;
}
__device__ __forceinline__ void permswap32(unsigned &a, unsigned &b) {
    asm volatile("v_permlane32_swap_b32 %0, %1" : "+v"(a), "+v"(b));
}

// ---------------------------------------------------------------------------
// FRAGMENT-MAJOR layouts (r13/r15: K -> LDS pipe conflict-free, V -> L2/TCP
// pipe coalesced; SQ_LDS_BANK_CONFLICT = 0 measured in r15):
//   KF[b][st 64][it 2][kk 4][g2 2][r31 32][e 8]  bf16  (4 MB)
//     element = K[key=st*64+it*32+r31][ch=kk*16+g2*8+e]
//   VF[b][st 64][it 2][h 2][c 2][g2 2][r31 32][e 8]  bf16  (4 MB)
//     element = V[ch=h*32+r31][key=st*64+it*32+c*16+g2*8+e]
// A wave reads any fragment as base + lane*16 -> coalesced 1KB (global) or
// conflict-free contiguous (LDS).
// ---------------------------------------------------------------------------

// Kernel 1: both 1x1 convs. Grid 4096 = (b, nb, pass, oq); 64 threads.
__global__ __launch_bounds__(64)
void conv_prep(const float* __restrict__ xlow, const float* __restrict__ xhigh,
               const float* __restrict__ Wl, const float* __restrict__ bl,
               const float* __restrict__ Wh, const float* __restrict__ bh,
               unsigned short* __restrict__ KF, unsigned short* __restrict__ QThi,
               unsigned short* __restrict__ VF, float* __restrict__ R32)
{
    const int id   = blockIdx.x;
    const int b    = id & 7;
    const int rest = id >> 3;
    const int nb   = rest & 63;
    const int pass = (rest >> 6) & 1;  // 0 = low (K), 1 = high (Q/V/R)
    const int oq   = rest >> 7;        // 0..3 channel quarter
    const int t    = threadIdx.x;
    const int n    = nb * 64 + t;
    const int o0   = oq * 16;

    const float* __restrict__ x    = pass ? xhigh : xlow;
    const float* __restrict__ W    = pass ? Wh : Wl;
    const float* __restrict__ bias = pass ? bh : bl;

    float xr[64];
#pragma unroll
    for (int i = 0; i < 64; ++i)
        xr[i] = x[((size_t)(b * 64 + i)) * NPOS + n];

    // VF scatter base: st=nb, it=(t>>5)&1, c=(t>>4)&1, g2=(t>>3)&1, e=t&7;
    // h=oq>>1, r31=(oq&1)*16+oo -> + (oq&1)*256 + oo*16
    char* vbase = (char*)VF + ((size_t)b << 19) + nb * 8192 + ((t >> 5) & 1) * 4096
                + (oq >> 1) * 2048 + ((t >> 4) & 1) * 1024 + ((t >> 3) & 1) * 512
                + (oq & 1) * 256 + (t & 7) * 2;

    unsigned hpack[8];
#pragma unroll
    for (int oo = 0; oo < 16; ++oo) {
        const int o = o0 + oo;
        float acc = bias[o];
#pragma unroll
        for (int i = 0; i < 64; ++i)
            acc = fmaf(W[o * 64 + i], xr[i], acc);   // W reads wave-uniform -> s_load

        if (pass) {
            *(unsigned short*)(vbase + oo * 16) = bf_rne(acc);
            R32[((size_t)(b * 64 + o)) * NPOS + n] = acc;
        }
        unsigned short h = bf_rne(pass ? acc * LOG2E : acc);
        if (oo & 1) hpack[oo >> 1] |= ((unsigned)h) << 16;
        else        hpack[oo >> 1]  = h;
    }

    if (pass) {
        // Q row-major (per-block prologue gather in attn -- once per wave)
        uint4* ph = (uint4*)(QThi + ((size_t)(b * NPOS + n)) * 64 + o0);
        uint4 v0; v0.x = hpack[0]; v0.y = hpack[1]; v0.z = hpack[2]; v0.w = hpack[3];
        uint4 v1; v1.x = hpack[4]; v1.y = hpack[5]; v1.z = hpack[6]; v1.w = hpack[7];
        ph[0] = v0; ph[1] = v1;
    } else {
        // KF frag-major: key=n -> st=nb, it=(t>>5)&1, r31=t&31; kk=oq, g2=oo>>3
        char* kbase = (char*)KF + ((size_t)b << 19) + nb * 8192 + ((t >> 5) & 1) * 4096
                    + oq * 1024 + (t & 31) * 16;
        uint4 v0; v0.x = hpack[0]; v0.y = hpack[1]; v0.z = hpack[2]; v0.w = hpack[3];
        uint4 v1; v1.x = hpack[4]; v1.y = hpack[5]; v1.z = hpack[6]; v1.w = hpack[7];
        *(uint4*)kbase         = v0;   // g2=0
        *(uint4*)(kbase + 512) = v1;   // g2=1
    }
}

// ---------------------------------------------------------------------------
// K staging: one 8KB supertile of KF -> linear LDS; each wave copies a
// contiguous 1KB chunk. global_load_lds source is PER-LANE (+lane*16);
// LDS dest = uniform base + lane*16 (r14 bug lesson).
// ---------------------------------------------------------------------------
__device__ __forceinline__ void stage_k(const unsigned short* __restrict__ KF,
                                        int b, int st, char* dst, int w, int lane)
{
    const char* src = (const char*)KF + ((size_t)b << 19) + (size_t)st * 8192
                    + w * 1024 + lane * 16;
    __builtin_amdgcn_global_load_lds(
        (const __attribute__((address_space(1))) unsigned int*)(const void*)src,
        (__attribute__((address_space(3))) unsigned int*)(void*)(dst + w * 1024),
        16, 0, 0);
}

// ---------------------------------------------------------------------------
// Kernel 2: flash attention partials. 8 waves x 32 q-rows = 256 q/block.
// Grid = 8 b x 16 qb x nsplit(4) = 512 blocks = 2 blocks/CU.
// K: LDS (conflict-free). V: global frag-major, DEPTH-2 SOFTWARE PIPELINE.
// REGALLOC (r16 post-mortem): the backend's default waves-per-eu range made
// it target 8 waves/EU = 64 VGPR and SPILL the ~110-reg live set (FETCH
// 26.5 MB, WRITE 153 MB of scratch, 2x slowdown). amdgpu_waves_per_eu(4,4)
// pins the target: allocator may use up to 128 VGPR spill-free; 4 waves/EU
// x 4 SIMD = 16 waves/CU = 2 blocks/CU residency (r11/r15: sufficient).
// FIXED-SCALE softmax (validated r7-r16): p = exp2(sA), plain-sum combine.
// ---------------------------------------------------------------------------
__global__ __launch_bounds__(512) __attribute__((amdgpu_waves_per_eu(4, 4)))
void attn_fused(const unsigned short* __restrict__ KF,
                const unsigned short* __restrict__ QThi,
                const unsigned short* __restrict__ VF,
                unsigned short* __restrict__ Pacc, float* __restrict__ Lp,
                int nsplit)
{
    const int id   = blockIdx.x;
    const int b    = id & 7;            // one batch per XCD
    const int qb   = (id >> 3) & 15;    // q-block (256 rows)
    const int s    = id >> 7;           // KV split index
    const int tid  = threadIdx.x;
    const int w    = tid >> 6;          // 0..7
    const int lane = tid & 63;
    const int r31  = lane & 31;
    const int g2   = lane >> 5;

    const int st0 = (64 * s) / nsplit;
    const int nst = (64 * (s + 1)) / nsplit - st0;

    __shared__ __align__(1024) char smem[16384];   // 2 x 8KB K supertile buffers

    // Q fragments hoisted (B-operand: col=lane&31=q, k=(lane>>5)*8+e)
    const int qrow = qb * 256 + w * 32 + r31;
    bf16x8 qhi[4];
#pragma unroll
    for (int kk = 0; kk < 4; ++kk)
        qhi[kk] = *(const bf16x8*)(QThi + ((size_t)b * NPOS + qrow) * 64 + kk * 16 + g2 * 8);

    f32x16 accO0, accO1;
#pragma unroll
    for (int r = 0; r < 16; ++r) { accO0[r] = 0.f; accO1[r] = 0.f; }
    float l_run = 0.f;

    stage_k(KF, b, st0, smem, w, lane);
    __syncthreads();

    const int itA = (w & 1);        // wave-staggered phase order
    const int itB = itA ^ 1;

    for (int st = 0; st < nst; ++st) {
        char* buf = smem + (st & 1) * 8192;
        if (st + 1 < nst)
            stage_k(KF, b, st0 + st + 1, smem + ((st + 1) & 1) * 8192, w, lane);

        const char* vst = (const char*)VF + ((size_t)b << 19)
                        + (size_t)(st0 + st) * 8192 + lane * 16;

        // ---- V(itA): issue FIRST so latency hides under QK_A + softmax_A ----
        const char* vbA = vst + itA * 4096;
        bf16x8 vA00 = *(const bf16x8*)(vbA);
        bf16x8 vA01 = *(const bf16x8*)(vbA + 1024);
        bf16x8 vA10 = *(const bf16x8*)(vbA + 2048);
        bf16x8 vA11 = *(const bf16x8*)(vbA + 3072);

        // ---- QK^T (itA): K frags from LDS (conflict-free) ----
        f32x16 sA;
#pragma unroll
        for (int r = 0; r < 16; ++r) sA[r] = 0.f;
        {
            const char* Kb = buf + itA * 4096;
            __builtin_amdgcn_s_setprio(1);
#pragma unroll
            for (int kk = 0; kk < 4; ++kk) {
                bf16x8 kh = *(const bf16x8*)(Kb + kk * 1024 + lane * 16);
                sA = __builtin_amdgcn_mfma_f32_32x32x16_bf16(kh, qhi[kk], sA, 0, 0, 0);
            }
            __builtin_amdgcn_s_setprio(0);
        }

        // ---- V(itB) prefetch: hides under softmax_A + PV_A + QK_B ----
        const char* vbB = vst + itB * 4096;
        bf16x8 vB00 = *(const bf16x8*)(vbB);
        bf16x8 vB01 = *(const bf16x8*)(vbB + 1024);
        bf16x8 vB10 = *(const bf16x8*)(vbB + 2048);
        bf16x8 vB11 = *(const bf16x8*)(vbB + 3072);

        // ---- softmax_A (chunked, r9 spill fix) ----
        unsigned wpk[8];
        {
            float lr0 = 0.f, lr1 = 0.f;
#pragma unroll
            for (int h = 0; h < 8; ++h) {
                float pa = EXP2(sA[2 * h]);
                float pb = EXP2(sA[2 * h + 1]);
                wpk[h] = cvt_pk_bf16(pa, pb);
                lr0 += pa;
                lr1 += pb;
                if (h & 1) SOFTMAX_FENCE();
            }
            l_run += lr0 + lr1;
        }
        {
            unsigned a0 = wpk[0], b0 = wpk[2]; permswap32(a0, b0);
            unsigned a1 = wpk[1], b1 = wpk[3]; permswap32(a1, b1);
            unsigned a2 = wpk[4], b2 = wpk[6]; permswap32(a2, b2);
            unsigned a3 = wpk[5], b3 = wpk[7]; permswap32(a3, b3);
            union { unsigned u[4]; bf16x8 v; } fa0, fa1;
            fa0.u[0] = a0; fa0.u[1] = a1; fa0.u[2] = b0; fa0.u[3] = b1;
            fa1.u[0] = a2; fa1.u[1] = a3; fa1.u[2] = b2; fa1.u[3] = b3;

            // ---- PV_A (vA arrived long ago) ----
            __builtin_amdgcn_s_setprio(1);
            accO0 = __builtin_amdgcn_mfma_f32_32x32x16_bf16(vA00, fa0.v, accO0, 0, 0, 0);
            accO0 = __builtin_amdgcn_mfma_f32_32x32x16_bf16(vA01, fa1.v, accO0, 0, 0, 0);
            accO1 = __builtin_amdgcn_mfma_f32_32x32x16_bf16(vA10, fa0.v, accO1, 0, 0, 0);
            accO1 = __builtin_amdgcn_mfma_f32_32x32x16_bf16(vA11, fa1.v, accO1, 0, 0, 0);
            __builtin_amdgcn_s_setprio(0);
        }

        // ---- QK^T (itB) ----
#pragma unroll
        for (int r = 0; r < 16; ++r) sA[r] = 0.f;
        {
            const char* Kb = buf + itB * 4096;
            __builtin_amdgcn_s_setprio(1);
#pragma unroll
            for (int kk = 0; kk < 4; ++kk) {
                bf16x8 kh = *(const bf16x8*)(Kb + kk * 1024 + lane * 16);
                sA = __builtin_amdgcn_mfma_f32_32x32x16_bf16(kh, qhi[kk], sA, 0, 0, 0);
            }
            __builtin_amdgcn_s_setprio(0);
        }

        // ---- softmax_B ----
        {
            float lr0 = 0.f, lr1 = 0.f;
#pragma unroll
            for (int h = 0; h < 8; ++h) {
                float pa = EXP2(sA[2 * h]);
                float pb = EXP2(sA[2 * h + 1]);
                wpk[h] = cvt_pk_bf16(pa, pb);
                lr0 += pa;
                lr1 += pb;
                if (h & 1) SOFTMAX_FENCE();
            }
            l_run += lr0 + lr1;
        }
        {
            unsigned a0 = wpk[0], b0 = wpk[2]; permswap32(a0, b0);
            unsigned a1 = wpk[1], b1 = wpk[3]; permswap32(a1, b1);
            unsigned a2 = wpk[4], b2 = wpk[6]; permswap32(a2, b2);
            unsigned a3 = wpk[5], b3 = wpk[7]; permswap32(a3, b3);
            union { unsigned u[4]; bf16x8 v; } fa0, fa1;
            fa0.u[0] = a0; fa0.u[1] = a1; fa0.u[2] = b0; fa0.u[3] = b1;
            fa1.u[0] = a2; fa1.u[1] = a3; fa1.u[2] = b2; fa1.u[3] = b3;

            // ---- PV_B (vB prefetched) ----
            __builtin_amdgcn_s_setprio(1);
            accO0 = __builtin_amdgcn_mfma_f32_32x32x16_bf16(vB00, fa0.v, accO0, 0, 0, 0);
            accO0 = __builtin_amdgcn_mfma_f32_32x32x16_bf16(vB01, fa1.v, accO0, 0, 0, 0);
            accO1 = __builtin_amdgcn_mfma_f32_32x32x16_bf16(vB10, fa0.v, accO1, 0, 0, 0);
            accO1 = __builtin_amdgcn_mfma_f32_32x32x16_bf16(vB11, fa1.v, accO1, 0, 0, 0);
            __builtin_amdgcn_s_setprio(0);
        }

        __syncthreads();   // K dbuf safety; drains staging vmcnt
    }

    // ---- epilogue: bf16 partials, O^T layout [64 d][256 q]; l reduced once ----
    const float l_tot = l_run + __shfl_xor(l_run, 32, 64);
#pragma unroll
    for (int r = 0; r < 16; ++r) {
        const int d0 = (r & 3) + 8 * (r >> 2) + 4 * g2;
        Pacc[(size_t)id * 16384 + (size_t)d0 * 256 + w * 32 + r31]        = bf_rne(accO0[r]);
        Pacc[(size_t)id * 16384 + (size_t)(d0 + 32) * 256 + w * 32 + r31] = bf_rne(accO1[r]);
    }
    if (g2 == 0)
        Lp[(size_t)id * 256 + w * 32 + r31] = l_tot;
}

// ---------------------------------------------------------------------------
// Kernel 3: combine = plain sum of bf16 partials / sum of l + residual.
// LINE-ONCE reads (r13 fix): s outer, 32B contiguous per thread/split.
// ---------------------------------------------------------------------------
__global__ __launch_bounds__(256)
void attn_combine(const unsigned short* __restrict__ Pacc, const float* __restrict__ Lp,
                  const float* __restrict__ R32, float* __restrict__ out, int nsplit)
{
    const int cid     = blockIdx.x;
    const int quarter = cid & 3;
    const int b       = (cid >> 2) & 7;
    const int qb      = cid >> 5;        // 0..15
    const int t       = threadIdx.x;

    __shared__ float invL[256];

    {
        float L = 0.f;
        for (int s = 0; s < nsplit; ++s)
            L += Lp[(size_t)((s << 7) | (qb << 3) | b) * 256 + t];
        invL[t] = 1.0f / L;
    }
    __syncthreads();

    const int c_loc = t >> 4;                 // 0..15
    const int c     = quarter * 16 + c_loc;   // 0..63
    const int q0    = (t & 15) * 16;          // 0..240

    float acc[16];
#pragma unroll
    for (int i = 0; i < 16; ++i) acc[i] = 0.f;

    for (int s = 0; s < nsplit; ++s) {
        const size_t p = (size_t)((s << 7) | (qb << 3) | b);
        const bf16x8* pp = (const bf16x8*)(Pacc + p * 16384 + (size_t)c * 256 + q0);
#pragma unroll
        for (int h = 0; h < 2; ++h) {
            bf16x8 v = pp[h];
#pragma unroll
            for (int e = 0; e < 8; ++e)
                acc[h * 8 + e] += __uint_as_float(((unsigned)(unsigned short)v[e]) << 16);
        }
    }

    const size_t obase = ((size_t)(b * 64 + c)) * NPOS + qb * 256 + q0;
#pragma unroll
    for (int hv = 0; hv < 4; ++hv) {
        f32x4 rv = *(const f32x4*)(R32 + obase + hv * 4);
        f32x4 v;
#pragma unroll
        for (int e = 0; e < 4; ++e)
            v[e] = acc[hv * 4 + e] * invL[q0 + hv * 4 + e] + rv[e];
        *(f32x4*)(out + obase + hv * 4) = v;
    }
}

// ---------------------------------------------------------------------------
extern "C" void kernel_launch(void* const* d_in, const int* in_sizes, int n_in,
                              void* d_out, int out_size, void* d_ws, size_t ws_size,
                              hipStream_t stream)
{
    const float* xlow  = (const float*)d_in[0];
    const float* xhigh = (const float*)d_in[1];
    const float* Wl    = (const float*)d_in[2];
    const float* bl    = (const float*)d_in[3];
    const float* Wh    = (const float*)d_in[4];
    const float* bh    = (const float*)d_in[5];

    char* ws = (char*)d_ws;
    unsigned short* KF   = (unsigned short*)(ws);                  // 4 MB frag-major
    unsigned short* QThi = (unsigned short*)(ws + ( 4u << 20));    // 4 MB row-major
    unsigned short* VF   = (unsigned short*)(ws + ( 8u << 20));    // 4 MB frag-major
    float*          R32  = (float*)         (ws + (12u << 20));    // 8 MB -> 20 MB

    const size_t base = (size_t)20u << 20;
    // nsplit=4 -> grid 512 = exactly 2 blocks/CU (r11/r15: 16 waves/CU is
    // the TLP plateau; halves Pacc + combine traffic vs nsplit=8).
    int nsplit = 4;
    while (nsplit > 1) {
        size_t nblk = (size_t)128 * nsplit;
        size_t need = base + nblk * 16384 * 2 + nblk * 256 * 4;
        if (need <= ws_size) break;
        nsplit >>= 1;
    }
    const size_t nblk = (size_t)128 * nsplit;
    unsigned short* Pacc = (unsigned short*)(ws + base);
    float*          Lp   = (float*)(ws + base + nblk * 16384 * 2);

    conv_prep<<<dim3(4096), dim3(64), 0, stream>>>(
        xlow, xhigh, Wl, bl, Wh, bh, KF, QThi, VF, R32);
    attn_fused<<<dim3((unsigned)nblk), dim3(512), 0, stream>>>(
        KF, QThi, VF, Pacc, Lp, nsplit);
    attn_combine<<<dim3(512), dim3(256), 0, stream>>>(
        Pacc, Lp, R32, (float*)d_out, nsplit);
}

// Round 20
// 84.988 us; speedup vs baseline: 1.3690x; 1.3683x over previous
//
#include <hip/hip_runtime.h>
#include <hip/hip_bf16.h>
#include <stdint.h>

#define BATCH 8
#define NPOS 4096   // H*W = 64*64
#define LOG2E 1.4426950408889634f

typedef __attribute__((ext_vector_type(2)))  float f32x2;
typedef __attribute__((ext_vector_type(4)))  float f32x4;
typedef __attribute__((ext_vector_type(16))) float f32x16;
typedef __attribute__((ext_vector_type(8)))  short bf16x8;

// Native 2^x. Raw inline-asm v_exp_f32 is UNSAFE (r6: TRANS hazard invisible).
// Builtin is compiler-visible. r9 lesson: must pair with chunked
// immediate-consume + sched_barrier or the scheduler hoists all 16 exps ->
// spill cliff (r10-r15: pattern works, no spills).
#if __has_builtin(__builtin_amdgcn_exp2f)
#define EXP2(x) __builtin_amdgcn_exp2f(x)
#else
#define EXP2(x) exp2f(x)
#endif

// sched_barrier mask: MFMA|VMEM*|DS* may cross, VALU/TRANS/SALU may not.
#define SOFTMAX_FENCE() __builtin_amdgcn_sched_barrier(0x3F8)

__device__ __forceinline__ unsigned short bf_rne(float f) {
    unsigned u = __float_as_uint(f);
    u += 0x7fffu + ((u >> 16) & 1u);
    return (unsigned short)(u >> 16);
}
__device__ __forceinline__ unsigned cvt_pk_bf16(float lo, float hi) {
    unsigned r;
    asm("v_cvt_pk_bf16_f32 %0, %1, %2" : "=v"(r) : "v"(lo), "v"(hi));
    return r;
}
__device__ __forceinline__ void permswap32(unsigned &a, unsigned &b) {
    asm volatile("v_permlane32_swap_b32 %0, %1" : "+v"(a), "+v"(b));
}

// ---------------------------------------------------------------------------
// FRAGMENT-MAJOR layouts (r13/r15: K -> LDS pipe conflict-free, V -> L2/TCP
// pipe coalesced; SQ_LDS_BANK_CONFLICT = 0 measured in r15):
//   KF[b][st 64][it 2][kk 4][g2 2][r31 32][e 8]  bf16  (4 MB)
//     element = K[key=st*64+it*32+r31][ch=kk*16+g2*8+e]
//   VF[b][st 64][it 2][h 2][c 2][g2 2][r31 32][e 8]  bf16  (4 MB)
//     element = V[ch=h*32+r31][key=st*64+it*32+c*16+g2*8+e]
// A wave reads any fragment as base + lane*16 -> coalesced 1KB (global) or
// conflict-free contiguous (LDS).
//
// REGALLOC VERDICT (r16/r19): depth-2 V pipelining does NOT fit -- the
// backend pins VGPR_Count=64 for this kernel and ignores both
// launch_bounds(512,4)'s 128 cap and amdgpu_waves_per_eu(4,4); the extra
// 16 live regs become 150+ MB of scratch traffic (2x slowdown). attn is
// therefore the r15 single-issue structure. DO NOT re-add the pipeline.
// ---------------------------------------------------------------------------

// Kernel 1: both 1x1 convs. Grid 4096 = (b, nb, pass, oq); 64 threads.
// Output channels processed in PAIRS via f32x2 elementwise_fma -> clang
// lowers to v_pk_fma_f32 (2 FMA/instr) on gfx950; each pair lane is the
// same serial chain as the scalar version -> bitwise-identical results.
__global__ __launch_bounds__(64)
void conv_prep(const float* __restrict__ xlow, const float* __restrict__ xhigh,
               const float* __restrict__ Wl, const float* __restrict__ bl,
               const float* __restrict__ Wh, const float* __restrict__ bh,
               unsigned short* __restrict__ KF, unsigned short* __restrict__ QThi,
               unsigned short* __restrict__ VF, float* __restrict__ R32)
{
    const int id   = blockIdx.x;
    const int b    = id & 7;
    const int rest = id >> 3;
    const int nb   = rest & 63;
    const int pass = (rest >> 6) & 1;  // 0 = low (K), 1 = high (Q/V/R)
    const int oq   = rest >> 7;        // 0..3 channel quarter
    const int t    = threadIdx.x;
    const int n    = nb * 64 + t;
    const int o0   = oq * 16;

    const float* __restrict__ x    = pass ? xhigh : xlow;
    const float* __restrict__ W    = pass ? Wh : Wl;
    const float* __restrict__ bias = pass ? bh : bl;

    float xr[64];
#pragma unroll
    for (int i = 0; i < 64; ++i)
        xr[i] = x[((size_t)(b * 64 + i)) * NPOS + n];

    // VF scatter base: st=nb, it=(t>>5)&1, c=(t>>4)&1, g2=(t>>3)&1, e=t&7;
    // h=oq>>1, r31=(oq&1)*16+oo -> + (oq&1)*256 + oo*16
    char* vbase = (char*)VF + ((size_t)b << 19) + nb * 8192 + ((t >> 5) & 1) * 4096
                + (oq >> 1) * 2048 + ((t >> 4) & 1) * 1024 + ((t >> 3) & 1) * 512
                + (oq & 1) * 256 + (t & 7) * 2;

    unsigned hpack[8];
#pragma unroll
    for (int op = 0; op < 8; ++op) {               // channel pair
        const int o = o0 + op * 2;
        f32x2 acc2 = { bias[o], bias[o + 1] };
#pragma unroll
        for (int i = 0; i < 64; ++i) {
            f32x2 w2 = { W[o * 64 + i], W[(o + 1) * 64 + i] };  // wave-uniform -> s_load
            f32x2 x2 = { xr[i], xr[i] };
            acc2 = __builtin_elementwise_fma(w2, x2, acc2);     // v_pk_fma_f32
        }

        if (pass) {
            *(unsigned short*)(vbase + (op * 2 + 0) * 16) = bf_rne(acc2[0]);
            *(unsigned short*)(vbase + (op * 2 + 1) * 16) = bf_rne(acc2[1]);
            R32[((size_t)(b * 64 + o)) * NPOS + n]     = acc2[0];
            R32[((size_t)(b * 64 + o + 1)) * NPOS + n] = acc2[1];
        }
        unsigned short h0 = bf_rne(pass ? acc2[0] * LOG2E : acc2[0]);
        unsigned short h1 = bf_rne(pass ? acc2[1] * LOG2E : acc2[1]);
        hpack[op] = (unsigned)h0 | (((unsigned)h1) << 16);
    }

    if (pass) {
        // Q row-major (per-block prologue gather in attn -- once per wave)
        uint4* ph = (uint4*)(QThi + ((size_t)(b * NPOS + n)) * 64 + o0);
        uint4 v0; v0.x = hpack[0]; v0.y = hpack[1]; v0.z = hpack[2]; v0.w = hpack[3];
        uint4 v1; v1.x = hpack[4]; v1.y = hpack[5]; v1.z = hpack[6]; v1.w = hpack[7];
        ph[0] = v0; ph[1] = v1;
    } else {
        // KF frag-major: key=n -> st=nb, it=(t>>5)&1, r31=t&31; kk=oq, g2=oo>>3
        char* kbase = (char*)KF + ((size_t)b << 19) + nb * 8192 + ((t >> 5) & 1) * 4096
                    + oq * 1024 + (t & 31) * 16;
        uint4 v0; v0.x = hpack[0]; v0.y = hpack[1]; v0.z = hpack[2]; v0.w = hpack[3];
        uint4 v1; v1.x = hpack[4]; v1.y = hpack[5]; v1.z = hpack[6]; v1.w = hpack[7];
        *(uint4*)kbase         = v0;   // g2=0
        *(uint4*)(kbase + 512) = v1;   // g2=1
    }
}

// ---------------------------------------------------------------------------
// K staging: one 8KB supertile of KF -> linear LDS; each wave copies a
// contiguous 1KB chunk. global_load_lds source is PER-LANE (+lane*16);
// LDS dest = uniform base + lane*16 (r14 bug lesson).
// ---------------------------------------------------------------------------
__device__ __forceinline__ void stage_k(const unsigned short* __restrict__ KF,
                                        int b, int st, char* dst, int w, int lane)
{
    const char* src = (const char*)KF + ((size_t)b << 19) + (size_t)st * 8192
                    + w * 1024 + lane * 16;
    __builtin_amdgcn_global_load_lds(
        (const __attribute__((address_space(1))) unsigned int*)(const void*)src,
        (__attribute__((address_space(3))) unsigned int*)(void*)(dst + w * 1024),
        16, 0, 0);
}

// ---------------------------------------------------------------------------
// Kernel 2: flash attention partials -- r15 STRUCTURE (single V issue per
// half-step; the depth-2 pipeline spills at the backend's hard 64-VGPR
// choice, r16/r19). 8 waves x 32 q-rows = 256 q/block.
// Grid = 8 b x 16 qb x nsplit(4) = 512 blocks = 2 blocks/CU = 16 waves/CU
// (r11: 2/CU measured >= 4/CU; halves Pacc vs nsplit=8).
// K: LDS conflict-free; V: global frag-major coalesced (L2-resident).
// FIXED-SCALE softmax (validated r7-r15): p = exp2(sA), plain-sum combine.
// Wave-staggered it order de-locksteps phases. bf16 partials.
// ---------------------------------------------------------------------------
__global__ __launch_bounds__(512, 4)
void attn_fused(const unsigned short* __restrict__ KF,
                const unsigned short* __restrict__ QThi,
                const unsigned short* __restrict__ VF,
                unsigned short* __restrict__ Pacc, float* __restrict__ Lp,
                int nsplit)
{
    const int id   = blockIdx.x;
    const int b    = id & 7;            // one batch per XCD
    const int qb   = (id >> 3) & 15;    // q-block (256 rows)
    const int s    = id >> 7;           // KV split index
    const int tid  = threadIdx.x;
    const int w    = tid >> 6;          // 0..7
    const int lane = tid & 63;
    const int r31  = lane & 31;
    const int g2   = lane >> 5;

    const int st0 = (64 * s) / nsplit;
    const int nst = (64 * (s + 1)) / nsplit - st0;

    __shared__ __align__(1024) char smem[16384];   // 2 x 8KB K supertile buffers

    // Q fragments hoisted (B-operand: col=lane&31=q, k=(lane>>5)*8+e)
    const int qrow = qb * 256 + w * 32 + r31;
    bf16x8 qhi[4];
#pragma unroll
    for (int kk = 0; kk < 4; ++kk)
        qhi[kk] = *(const bf16x8*)(QThi + ((size_t)b * NPOS + qrow) * 64 + kk * 16 + g2 * 8);

    f32x16 accO0, accO1;
#pragma unroll
    for (int r = 0; r < 16; ++r) { accO0[r] = 0.f; accO1[r] = 0.f; }
    float l_run = 0.f;

    stage_k(KF, b, st0, smem, w, lane);
    __syncthreads();

    for (int st = 0; st < nst; ++st) {
        char* buf = smem + (st & 1) * 8192;
        if (st + 1 < nst)
            stage_k(KF, b, st0 + st + 1, smem + ((st + 1) & 1) * 8192, w, lane);

#pragma unroll
        for (int itx = 0; itx < 2; ++itx) {
            const int it = itx ^ (w & 1);   // wave-staggered phase order

            // ---- QK^T: K frags from LDS (lane-contiguous, conflict-free) ----
            f32x16 sA;
#pragma unroll
            for (int r = 0; r < 16; ++r) sA[r] = 0.f;
            const char* Kb = buf + it * 4096;
            __builtin_amdgcn_s_setprio(1);
#pragma unroll
            for (int kk = 0; kk < 4; ++kk) {
                bf16x8 kh = *(const bf16x8*)(Kb + kk * 1024 + lane * 16);
                sA = __builtin_amdgcn_mfma_f32_32x32x16_bf16(kh, qhi[kk], sA, 0, 0, 0);
            }
            __builtin_amdgcn_s_setprio(0);

            // ---- V frags from GLOBAL (issued here; latency hides under
            // softmax; coalesced 1KB/wave-load, L2-resident) ----
            const char* vbase = (const char*)VF + ((size_t)b << 19)
                              + (size_t)(st0 + st) * 8192 + it * 4096 + lane * 16;
            bf16x8 vf00 = *(const bf16x8*)(vbase);          // h=0 c=0
            bf16x8 vf01 = *(const bf16x8*)(vbase + 1024);   // h=0 c=1
            bf16x8 vf10 = *(const bf16x8*)(vbase + 2048);   // h=1 c=0
            bf16x8 vf11 = *(const bf16x8*)(vbase + 3072);   // h=1 c=1

            // ---- fixed-scale softmax, chunked (r9 spill fix) ----
            unsigned wpk[8];
            float lr0 = 0.f, lr1 = 0.f;
#pragma unroll
            for (int h = 0; h < 8; ++h) {
                float pa = EXP2(sA[2 * h]);
                float pb = EXP2(sA[2 * h + 1]);
                wpk[h] = cvt_pk_bf16(pa, pb);
                lr0 += pa;
                lr1 += pb;
                if (h & 1) SOFTMAX_FENCE();
            }
            l_run += lr0 + lr1;

            // ---- P half-exchange (permlane32_swap) -> B-frags ----
            unsigned a0 = wpk[0], b0 = wpk[2]; permswap32(a0, b0);
            unsigned a1 = wpk[1], b1 = wpk[3]; permswap32(a1, b1);
            unsigned a2 = wpk[4], b2 = wpk[6]; permswap32(a2, b2);
            unsigned a3 = wpk[5], b3 = wpk[7]; permswap32(a3, b3);
            union { unsigned u[4]; bf16x8 v; } fa0, fa1;
            fa0.u[0] = a0; fa0.u[1] = a1; fa0.u[2] = b0; fa0.u[3] = b1;
            fa1.u[0] = a2; fa1.u[1] = a3; fa1.u[2] = b2; fa1.u[3] = b3;

            // ---- PV: O^T += V^T · P ----
            __builtin_amdgcn_s_setprio(1);
            accO0 = __builtin_amdgcn_mfma_f32_32x32x16_bf16(vf00, fa0.v, accO0, 0, 0, 0);
            accO0 = __builtin_amdgcn_mfma_f32_32x32x16_bf16(vf01, fa1.v, accO0, 0, 0, 0);
            accO1 = __builtin_amdgcn_mfma_f32_32x32x16_bf16(vf10, fa0.v, accO1, 0, 0, 0);
            accO1 = __builtin_amdgcn_mfma_f32_32x32x16_bf16(vf11, fa1.v, accO1, 0, 0, 0);
            __builtin_amdgcn_s_setprio(0);
        }
        __syncthreads();   // K dbuf safety; drains staging vmcnt (1 load/wave)
    }

    // ---- epilogue: bf16 partials, O^T layout [64 d][256 q]; l reduced once ----
    const float l_tot = l_run + __shfl_xor(l_run, 32, 64);
#pragma unroll
    for (int r = 0; r < 16; ++r) {
        const int d0 = (r & 3) + 8 * (r >> 2) + 4 * g2;
        Pacc[(size_t)id * 16384 + (size_t)d0 * 256 + w * 32 + r31]        = bf_rne(accO0[r]);
        Pacc[(size_t)id * 16384 + (size_t)(d0 + 32) * 256 + w * 32 + r31] = bf_rne(accO1[r]);
    }
    if (g2 == 0)
        Lp[(size_t)id * 256 + w * 32 + r31] = l_tot;
}

// ---------------------------------------------------------------------------
// Kernel 3: combine = plain sum of bf16 partials / sum of l + residual.
// LINE-ONCE reads (r13 fix): s outer, 32B contiguous per thread/split.
// nsplit=4 -> Pacc 16.8 MB -> ~25 MB read vs r15's 42 MB.
// ---------------------------------------------------------------------------
__global__ __launch_bounds__(256)
void attn_combine(const unsigned short* __restrict__ Pacc, const float* __restrict__ Lp,
                  const float* __restrict__ R32, float* __restrict__ out, int nsplit)
{
    const int cid     = blockIdx.x;
    const int quarter = cid & 3;
    const int b       = (cid >> 2) & 7;
    const int qb      = cid >> 5;        // 0..15
    const int t       = threadIdx.x;

    __shared__ float invL[256];

    {
        float L = 0.f;
        for (int s = 0; s < nsplit; ++s)
            L += Lp[(size_t)((s << 7) | (qb << 3) | b) * 256 + t];
        invL[t] = 1.0f / L;
    }
    __syncthreads();

    const int c_loc = t >> 4;                 // 0..15
    const int c     = quarter * 16 + c_loc;   // 0..63
    const int q0    = (t & 15) * 16;          // 0..240

    float acc[16];
#pragma unroll
    for (int i = 0; i < 16; ++i) acc[i] = 0.f;

    for (int s = 0; s < nsplit; ++s) {
        const size_t p = (size_t)((s << 7) | (qb << 3) | b);
        const bf16x8* pp = (const bf16x8*)(Pacc + p * 16384 + (size_t)c * 256 + q0);
#pragma unroll
        for (int h = 0; h < 2; ++h) {
            bf16x8 v = pp[h];
#pragma unroll
            for (int e = 0; e < 8; ++e)
                acc[h * 8 + e] += __uint_as_float(((unsigned)(unsigned short)v[e]) << 16);
        }
    }

    const size_t obase = ((size_t)(b * 64 + c)) * NPOS + qb * 256 + q0;
#pragma unroll
    for (int hv = 0; hv < 4; ++hv) {
        f32x4 rv = *(const f32x4*)(R32 + obase + hv * 4);
        f32x4 v;
#pragma unroll
        for (int e = 0; e < 4; ++e)
            v[e] = acc[hv * 4 + e] * invL[q0 + hv * 4 + e] + rv[e];
        *(f32x4*)(out + obase + hv * 4) = v;
    }
}

// ---------------------------------------------------------------------------
extern "C" void kernel_launch(void* const* d_in, const int* in_sizes, int n_in,
                              void* d_out, int out_size, void* d_ws, size_t ws_size,
                              hipStream_t stream)
{
    const float* xlow  = (const float*)d_in[0];
    const float* xhigh = (const float*)d_in[1];
    const float* Wl    = (const float*)d_in[2];
    const float* bl    = (const float*)d_in[3];
    const float* Wh    = (const float*)d_in[4];
    const float* bh    = (const float*)d_in[5];

    char* ws = (char*)d_ws;
    unsigned short* KF   = (unsigned short*)(ws);                  // 4 MB frag-major
    unsigned short* QThi = (unsigned short*)(ws + ( 4u << 20));    // 4 MB row-major
    unsigned short* VF   = (unsigned short*)(ws + ( 8u << 20));    // 4 MB frag-major
    float*          R32  = (float*)         (ws + (12u << 20));    // 8 MB -> 20 MB

    const size_t base = (size_t)20u << 20;
    // nsplit=4 -> grid 512 = exactly 2 blocks/CU (r11: >= 4/CU speed;
    // halves Pacc + combine traffic vs nsplit=8).
    int nsplit = 4;
    while (nsplit > 1) {
        size_t nblk = (size_t)128 * nsplit;
        size_t need = base + nblk * 16384 * 2 + nblk * 256 * 4;
        if (need <= ws_size) break;
        nsplit >>= 1;
    }
    const size_t nblk = (size_t)128 * nsplit;
    unsigned short* Pacc = (unsigned short*)(ws + base);
    float*          Lp   = (float*)(ws + base + nblk * 16384 * 2);

    conv_prep<<<dim3(4096), dim3(64), 0, stream>>>(
        xlow, xhigh, Wl, bl, Wh, bh, KF, QThi, VF, R32);
    attn_fused<<<dim3((unsigned)nblk), dim3(512), 0, stream>>>(
        KF, QThi, VF, Pacc, Lp, nsplit);
    attn_combine<<<dim3(512), dim3(256), 0, stream>>>(
        Pacc, Lp, R32, (float*)d_out, nsplit);
}

// Round 21
// 76.504 us; speedup vs baseline: 1.5208x; 1.1109x over previous
//
#include <hip/hip_runtime.h>
#include <hip/hip_bf16.h>
#include <stdint.h>

#define BATCH 8
#define NPOS 4096   // H*W = 64*64
#define LOG2E 1.4426950408889634f

typedef __attribute__((ext_vector_type(4)))  float f32x4;
typedef __attribute__((ext_vector_type(16))) float f32x16;
typedef __attribute__((ext_vector_type(8)))  short bf16x8;

// Native 2^x. Raw inline-asm v_exp_f32 is UNSAFE (r6: TRANS hazard invisible).
// Builtin is compiler-visible. r9 lesson: must pair with chunked
// immediate-consume + sched_barrier or the scheduler hoists all 16 exps ->
// spill cliff (r10-r20: pattern works, no spills).
#if __has_builtin(__builtin_amdgcn_exp2f)
#define EXP2(x) __builtin_amdgcn_exp2f(x)
#else
#define EXP2(x) exp2f(x)
#endif

// sched_barrier mask: MFMA|VMEM*|DS* may cross, VALU/TRANS/SALU may not.
#define SOFTMAX_FENCE() __builtin_amdgcn_sched_barrier(0x3F8)

__device__ __forceinline__ unsigned short bf_rne(float f) {
    unsigned u = __float_as_uint(f);
    u += 0x7fffu + ((u >> 16) & 1u);
    return (unsigned short)(u >> 16);
}
__device__ __forceinline__ unsigned cvt_pk_bf16(float lo, float hi) {
    unsigned r;
    asm("v_cvt_pk_bf16_f32 %0, %1, %2" : "=v"(r) : "v"(lo), "v"(hi));
    return r;
}
__device__ __forceinline__ void permswap32(unsigned &a, unsigned &b) {
    asm volatile("v_permlane32_swap_b32 %0, %1" : "+v"(a), "+v"(b));
}

// ---------------------------------------------------------------------------
// FRAGMENT-MAJOR layouts (r13/r15: K -> LDS pipe conflict-free, V -> L2/TCP
// pipe coalesced; SQ_LDS_BANK_CONFLICT = 0 measured in r15/r20):
//   KF[b][st 64][it 2][kk 4][g2 2][r31 32][e 8]  bf16  (4 MB)
//     element = K[key=st*64+it*32+r31][ch=kk*16+g2*8+e]
//   VF[b][st 64][it 2][h 2][c 2][g2 2][r31 32][e 8]  bf16  (4 MB)
//     element = V[ch=h*32+r31][key=st*64+it*32+c*16+g2*8+e]
//
// REGALLOC VERDICT (r16/r19): depth-2 V pipelining does NOT fit -- backend
// pins VGPR=64 regardless of launch_bounds/waves_per_eu attrs; extra live
// regs become 150+ MB scratch (2x slowdown). DO NOT re-add the pipeline.
// CONV VERDICT (r20): f32x2 elementwise_fma pairing REGRESSED ~9 us (broke
// the scalar s_load/fma chain; no v_pk_fma fusion). Keep scalar fmaf.
// ---------------------------------------------------------------------------

// Kernel 1: both 1x1 convs. Grid 4096 = (b, nb, pass, oq); 64 threads.
// Scalar fmaf chain; W/bias reads wave-uniform -> s_load (r15-proven ~14us).
__global__ __launch_bounds__(64)
void conv_prep(const float* __restrict__ xlow, const float* __restrict__ xhigh,
               const float* __restrict__ Wl, const float* __restrict__ bl,
               const float* __restrict__ Wh, const float* __restrict__ bh,
               unsigned short* __restrict__ KF, unsigned short* __restrict__ QThi,
               unsigned short* __restrict__ VF, float* __restrict__ R32)
{
    const int id   = blockIdx.x;
    const int b    = id & 7;
    const int rest = id >> 3;
    const int nb   = rest & 63;
    const int pass = (rest >> 6) & 1;  // 0 = low (K), 1 = high (Q/V/R)
    const int oq   = rest >> 7;        // 0..3 channel quarter
    const int t    = threadIdx.x;
    const int n    = nb * 64 + t;
    const int o0   = oq * 16;

    const float* __restrict__ x    = pass ? xhigh : xlow;
    const float* __restrict__ W    = pass ? Wh : Wl;
    const float* __restrict__ bias = pass ? bh : bl;

    float xr[64];
#pragma unroll
    for (int i = 0; i < 64; ++i)
        xr[i] = x[((size_t)(b * 64 + i)) * NPOS + n];

    // VF scatter base: st=nb, it=(t>>5)&1, c=(t>>4)&1, g2=(t>>3)&1, e=t&7;
    // h=oq>>1, r31=(oq&1)*16+oo -> + (oq&1)*256 + oo*16
    char* vbase = (char*)VF + ((size_t)b << 19) + nb * 8192 + ((t >> 5) & 1) * 4096
                + (oq >> 1) * 2048 + ((t >> 4) & 1) * 1024 + ((t >> 3) & 1) * 512
                + (oq & 1) * 256 + (t & 7) * 2;

    unsigned hpack[8];
#pragma unroll
    for (int oo = 0; oo < 16; ++oo) {
        const int o = o0 + oo;
        float acc = bias[o];
#pragma unroll
        for (int i = 0; i < 64; ++i)
            acc = fmaf(W[o * 64 + i], xr[i], acc);   // W reads wave-uniform -> s_load

        if (pass) {
            *(unsigned short*)(vbase + oo * 16) = bf_rne(acc);
            R32[((size_t)(b * 64 + o)) * NPOS + n] = acc;
        }
        unsigned short h = bf_rne(pass ? acc * LOG2E : acc);
        if (oo & 1) hpack[oo >> 1] |= ((unsigned)h) << 16;
        else        hpack[oo >> 1]  = h;
    }

    if (pass) {
        // Q row-major (per-block prologue gather in attn -- once per wave)
        uint4* ph = (uint4*)(QThi + ((size_t)(b * NPOS + n)) * 64 + o0);
        uint4 v0; v0.x = hpack[0]; v0.y = hpack[1]; v0.z = hpack[2]; v0.w = hpack[3];
        uint4 v1; v1.x = hpack[4]; v1.y = hpack[5]; v1.z = hpack[6]; v1.w = hpack[7];
        ph[0] = v0; ph[1] = v1;
    } else {
        // KF frag-major: key=n -> st=nb, it=(t>>5)&1, r31=t&31; kk=oq, g2=oo>>3
        char* kbase = (char*)KF + ((size_t)b << 19) + nb * 8192 + ((t >> 5) & 1) * 4096
                    + oq * 1024 + (t & 31) * 16;
        uint4 v0; v0.x = hpack[0]; v0.y = hpack[1]; v0.z = hpack[2]; v0.w = hpack[3];
        uint4 v1; v1.x = hpack[4]; v1.y = hpack[5]; v1.z = hpack[6]; v1.w = hpack[7];
        *(uint4*)kbase         = v0;   // g2=0
        *(uint4*)(kbase + 512) = v1;   // g2=1
    }
}

// ---------------------------------------------------------------------------
// K staging: one 8KB supertile of KF -> linear LDS; each wave copies a
// contiguous 1KB chunk. global_load_lds source is PER-LANE (+lane*16);
// LDS dest = uniform base + lane*16 (r14 bug lesson).
// ---------------------------------------------------------------------------
__device__ __forceinline__ void stage_k(const unsigned short* __restrict__ KF,
                                        int b, int st, char* dst, int w, int lane)
{
    const char* src = (const char*)KF + ((size_t)b << 19) + (size_t)st * 8192
                    + w * 1024 + lane * 16;
    __builtin_amdgcn_global_load_lds(
        (const __attribute__((address_space(1))) unsigned int*)(const void*)src,
        (__attribute__((address_space(3))) unsigned int*)(void*)(dst + w * 1024),
        16, 0, 0);
}

// ---------------------------------------------------------------------------
// Kernel 2: flash attention partials -- r15 structure (single V issue per
// half-step). 8 waves x 32 q-rows = 256 q/block.
// Grid = 8 b x 16 qb x nsplit(4) = 512 blocks = 2 blocks/CU = 16 waves/CU.
// K: LDS conflict-free; V: global frag-major coalesced (L2-resident).
// FIXED-SCALE softmax (validated r7-r20): p = exp2(sA), plain-sum combine.
// Wave-staggered it order de-locksteps phases. bf16 partials.
// ---------------------------------------------------------------------------
__global__ __launch_bounds__(512, 4)
void attn_fused(const unsigned short* __restrict__ KF,
                const unsigned short* __restrict__ QThi,
                const unsigned short* __restrict__ VF,
                unsigned short* __restrict__ Pacc, float* __restrict__ Lp,
                int nsplit)
{
    const int id   = blockIdx.x;
    const int b    = id & 7;            // one batch per XCD
    const int qb   = (id >> 3) & 15;    // q-block (256 rows)
    const int s    = id >> 7;           // KV split index
    const int tid  = threadIdx.x;
    const int w    = tid >> 6;          // 0..7
    const int lane = tid & 63;
    const int r31  = lane & 31;
    const int g2   = lane >> 5;

    const int st0 = (64 * s) / nsplit;
    const int nst = (64 * (s + 1)) / nsplit - st0;

    __shared__ __align__(1024) char smem[16384];   // 2 x 8KB K supertile buffers

    // Q fragments hoisted (B-operand: col=lane&31=q, k=(lane>>5)*8+e)
    const int qrow = qb * 256 + w * 32 + r31;
    bf16x8 qhi[4];
#pragma unroll
    for (int kk = 0; kk < 4; ++kk)
        qhi[kk] = *(const bf16x8*)(QThi + ((size_t)b * NPOS + qrow) * 64 + kk * 16 + g2 * 8);

    f32x16 accO0, accO1;
#pragma unroll
    for (int r = 0; r < 16; ++r) { accO0[r] = 0.f; accO1[r] = 0.f; }
    float l_run = 0.f;

    stage_k(KF, b, st0, smem, w, lane);
    __syncthreads();

    for (int st = 0; st < nst; ++st) {
        char* buf = smem + (st & 1) * 8192;
        if (st + 1 < nst)
            stage_k(KF, b, st0 + st + 1, smem + ((st + 1) & 1) * 8192, w, lane);

#pragma unroll
        for (int itx = 0; itx < 2; ++itx) {
            const int it = itx ^ (w & 1);   // wave-staggered phase order

            // ---- QK^T: K frags from LDS (lane-contiguous, conflict-free) ----
            f32x16 sA;
#pragma unroll
            for (int r = 0; r < 16; ++r) sA[r] = 0.f;
            const char* Kb = buf + it * 4096;
            __builtin_amdgcn_s_setprio(1);
#pragma unroll
            for (int kk = 0; kk < 4; ++kk) {
                bf16x8 kh = *(const bf16x8*)(Kb + kk * 1024 + lane * 16);
                sA = __builtin_amdgcn_mfma_f32_32x32x16_bf16(kh, qhi[kk], sA, 0, 0, 0);
            }
            __builtin_amdgcn_s_setprio(0);

            // ---- V frags from GLOBAL (issued here; latency hides under
            // softmax; coalesced 1KB/wave-load, L2-resident) ----
            const char* vbase = (const char*)VF + ((size_t)b << 19)
                              + (size_t)(st0 + st) * 8192 + it * 4096 + lane * 16;
            bf16x8 vf00 = *(const bf16x8*)(vbase);          // h=0 c=0
            bf16x8 vf01 = *(const bf16x8*)(vbase + 1024);   // h=0 c=1
            bf16x8 vf10 = *(const bf16x8*)(vbase + 2048);   // h=1 c=0
            bf16x8 vf11 = *(const bf16x8*)(vbase + 3072);   // h=1 c=1

            // ---- fixed-scale softmax, chunked (r9 spill fix) ----
            unsigned wpk[8];
            float lr0 = 0.f, lr1 = 0.f;
#pragma unroll
            for (int h = 0; h < 8; ++h) {
                float pa = EXP2(sA[2 * h]);
                float pb = EXP2(sA[2 * h + 1]);
                wpk[h] = cvt_pk_bf16(pa, pb);
                lr0 += pa;
                lr1 += pb;
                if (h & 1) SOFTMAX_FENCE();
            }
            l_run += lr0 + lr1;

            // ---- P half-exchange (permlane32_swap) -> B-frags ----
            unsigned a0 = wpk[0], b0 = wpk[2]; permswap32(a0, b0);
            unsigned a1 = wpk[1], b1 = wpk[3]; permswap32(a1, b1);
            unsigned a2 = wpk[4], b2 = wpk[6]; permswap32(a2, b2);
            unsigned a3 = wpk[5], b3 = wpk[7]; permswap32(a3, b3);
            union { unsigned u[4]; bf16x8 v; } fa0, fa1;
            fa0.u[0] = a0; fa0.u[1] = a1; fa0.u[2] = b0; fa0.u[3] = b1;
            fa1.u[0] = a2; fa1.u[1] = a3; fa1.u[2] = b2; fa1.u[3] = b3;

            // ---- PV: O^T += V^T · P ----
            __builtin_amdgcn_s_setprio(1);
            accO0 = __builtin_amdgcn_mfma_f32_32x32x16_bf16(vf00, fa0.v, accO0, 0, 0, 0);
            accO0 = __builtin_amdgcn_mfma_f32_32x32x16_bf16(vf01, fa1.v, accO0, 0, 0, 0);
            accO1 = __builtin_amdgcn_mfma_f32_32x32x16_bf16(vf10, fa0.v, accO1, 0, 0, 0);
            accO1 = __builtin_amdgcn_mfma_f32_32x32x16_bf16(vf11, fa1.v, accO1, 0, 0, 0);
            __builtin_amdgcn_s_setprio(0);
        }
        __syncthreads();   // K dbuf safety; drains staging vmcnt (1 load/wave)
    }

    // ---- epilogue: bf16 partials, O^T layout [64 d][256 q]; l reduced once ----
    const float l_tot = l_run + __shfl_xor(l_run, 32, 64);
#pragma unroll
    for (int r = 0; r < 16; ++r) {
        const int d0 = (r & 3) + 8 * (r >> 2) + 4 * g2;
        Pacc[(size_t)id * 16384 + (size_t)d0 * 256 + w * 32 + r31]        = bf_rne(accO0[r]);
        Pacc[(size_t)id * 16384 + (size_t)(d0 + 32) * 256 + w * 32 + r31] = bf_rne(accO1[r]);
    }
    if (g2 == 0)
        Lp[(size_t)id * 256 + w * 32 + r31] = l_tot;
}

// ---------------------------------------------------------------------------
// Kernel 3: combine = plain sum of bf16 partials / sum of l + residual.
// LINE-ONCE reads (r13 fix): s outer, 32B contiguous per thread/split.
// nsplit=4 -> Pacc 16.8 MB -> ~25 MB read.
// ---------------------------------------------------------------------------
__global__ __launch_bounds__(256)
void attn_combine(const unsigned short* __restrict__ Pacc, const float* __restrict__ Lp,
                  const float* __restrict__ R32, float* __restrict__ out, int nsplit)
{
    const int cid     = blockIdx.x;
    const int quarter = cid & 3;
    const int b       = (cid >> 2) & 7;
    const int qb      = cid >> 5;        // 0..15
    const int t       = threadIdx.x;

    __shared__ float invL[256];

    {
        float L = 0.f;
        for (int s = 0; s < nsplit; ++s)
            L += Lp[(size_t)((s << 7) | (qb << 3) | b) * 256 + t];
        invL[t] = 1.0f / L;
    }
    __syncthreads();

    const int c_loc = t >> 4;                 // 0..15
    const int c     = quarter * 16 + c_loc;   // 0..63
    const int q0    = (t & 15) * 16;          // 0..240

    float acc[16];
#pragma unroll
    for (int i = 0; i < 16; ++i) acc[i] = 0.f;

    for (int s = 0; s < nsplit; ++s) {
        const size_t p = (size_t)((s << 7) | (qb << 3) | b);
        const bf16x8* pp = (const bf16x8*)(Pacc + p * 16384 + (size_t)c * 256 + q0);
#pragma unroll
        for (int h = 0; h < 2; ++h) {
            bf16x8 v = pp[h];
#pragma unroll
            for (int e = 0; e < 8; ++e)
                acc[h * 8 + e] += __uint_as_float(((unsigned)(unsigned short)v[e]) << 16);
        }
    }

    const size_t obase = ((size_t)(b * 64 + c)) * NPOS + qb * 256 + q0;
#pragma unroll
    for (int hv = 0; hv < 4; ++hv) {
        f32x4 rv = *(const f32x4*)(R32 + obase + hv * 4);
        f32x4 v;
#pragma unroll
        for (int e = 0; e < 4; ++e)
            v[e] = acc[hv * 4 + e] * invL[q0 + hv * 4 + e] + rv[e];
        *(f32x4*)(out + obase + hv * 4) = v;
    }
}

// ---------------------------------------------------------------------------
extern "C" void kernel_launch(void* const* d_in, const int* in_sizes, int n_in,
                              void* d_out, int out_size, void* d_ws, size_t ws_size,
                              hipStream_t stream)
{
    const float* xlow  = (const float*)d_in[0];
    const float* xhigh = (const float*)d_in[1];
    const float* Wl    = (const float*)d_in[2];
    const float* bl    = (const float*)d_in[3];
    const float* Wh    = (const float*)d_in[4];
    const float* bh    = (const float*)d_in[5];

    char* ws = (char*)d_ws;
    unsigned short* KF   = (unsigned short*)(ws);                  // 4 MB frag-major
    unsigned short* QThi = (unsigned short*)(ws + ( 4u << 20));    // 4 MB row-major
    unsigned short* VF   = (unsigned short*)(ws + ( 8u << 20));    // 4 MB frag-major
    float*          R32  = (float*)         (ws + (12u << 20));    // 8 MB -> 20 MB

    const size_t base = (size_t)20u << 20;
    // nsplit=4 -> grid 512 = exactly 2 blocks/CU (r11/r20: >= 4/CU speed;
    // halves Pacc + combine traffic vs nsplit=8).
    int nsplit = 4;
    while (nsplit > 1) {
        size_t nblk = (size_t)128 * nsplit;
        size_t need = base + nblk * 16384 * 2 + nblk * 256 * 4;
        if (need <= ws_size) break;
        nsplit >>= 1;
    }
    const size_t nblk = (size_t)128 * nsplit;
    unsigned short* Pacc = (unsigned short*)(ws + base);
    float*          Lp   = (float*)(ws + base + nblk * 16384 * 2);

    conv_prep<<<dim3(4096), dim3(64), 0, stream>>>(
        xlow, xhigh, Wl, bl, Wh, bh, KF, QThi, VF, R32);
    attn_fused<<<dim3((unsigned)nblk), dim3(512), 0, stream>>>(
        KF, QThi, VF, Pacc, Lp, nsplit);
    attn_combine<<<dim3(512), dim3(256), 0, stream>>>(
        Pacc, Lp, R32, (float*)d_out, nsplit);
}